// Round 6
// baseline (23.686 us; speedup 1.0000x reference)
//
#include <hip/hip_runtime.h>

#define BATCH 2048
#define IND   256
#define OUTD  256

typedef __attribute__((ext_vector_type(8))) short bf16x8;
typedef __attribute__((ext_vector_type(4))) float f32x4;

#define AS1 __attribute__((address_space(1)))
#define AS3 __attribute__((address_space(3)))

__device__ __forceinline__ ushort f2bf(float f) {
    uint u = __builtin_bit_cast(uint, f);
    u += 0x7fffu + ((u >> 16) & 1u);          // RNE
    return (ushort)(u >> 16);
}
__device__ __forceinline__ uint pack2(float lo, float hi) {
    return (uint)f2bf(lo) | ((uint)f2bf(hi) << 16);
}

// ---------------- ws layout ----------------
#define BIASOFF (1u << 20)                 // WT: [0, 1MB)
#define FOFF    ((1u << 20) + 4096)        // F: 8MB
#define WS_NEED ((size_t)FOFF + (size_t)IND * BATCH * 16)

// features for one x value: [silu, B0..B6] (c7 folded: B7 = 1 - sum -> bias)
__device__ __forceinline__ uint4 feat_pack(float xv) {
    const float u = (xv + 1.0f) * 2.5f;
    float cif = floorf(u);
    cif = fminf(fmaxf(cif, 0.0f), 4.0f);
    const int ci = (int)cif;
    const float f = u - cif, mf = 1.0f - f;
    const float f2 = f * f, f3 = f2 * f;
    const float k6 = 1.0f / 6.0f;
    const float w0 = mf * mf * mf * k6;
    const float w1 = (3.0f * f3 - 6.0f * f2 + 4.0f) * k6;
    const float w3 = f3 * k6;
    const float w2 = 1.0f - w0 - w1 - w3;
    const float sg = __fdividef(xv, 1.0f + __expf(-xv));
    const float B0 = (ci == 0) ? w0 : 0.f;
    const float B1 = (ci == 1) ? w0 : (ci == 0) ? w1 : 0.f;
    const float B2 = (ci == 2) ? w0 : (ci == 1) ? w1 : (ci == 0) ? w2 : 0.f;
    const float B3 = (ci == 3) ? w0 : (ci == 2) ? w1 : (ci == 1) ? w2 : (ci == 0) ? w3 : 0.f;
    const float B4 = (ci == 4) ? w0 : (ci == 3) ? w1 : (ci == 2) ? w2 : (ci == 1) ? w3 : 0.f;
    const float B5 = (ci == 4) ? w1 : (ci == 3) ? w2 : (ci == 2) ? w3 : 0.f;
    const float B6 = (ci == 4) ? w2 : (ci == 3) ? w3 : 0.f;
    uint4 v;
    v.x = pack2(sg, B0); v.y = pack2(B1, B2);
    v.z = pack2(B3, B4); v.w = pack2(B5, B6);
    return v;
}

// ============ kernel 1: prep — 512 balanced blocks x 256 ============
// every block: F (row-major [b][i]) for 4 batch rows + W^T pack for one (i, o-half);
// blocks 480..511 additionally compute bias for 8 o's each.
__global__ __launch_bounds__(256) void kan_prep(
    const float* __restrict__ x, const float* __restrict__ coef,
    const float* __restrict__ sb, const float* __restrict__ ss,
    const float* __restrict__ mask,
    uint4* __restrict__ WT, float* __restrict__ bias, uint4* __restrict__ F)
{
    const int bid = blockIdx.x, tid = threadIdx.x;
    __shared__ float xt[4 * 260];
    __shared__ float part[32][8];

    // ---- load 4 x-rows (b0..b0+3) ----
    const int b0 = bid * 4;
    {
        const int row = tid >> 6, c4 = (tid & 63) * 4;
        const float4 v = *reinterpret_cast<const float4*>(
            x + (size_t)(b0 + row) * IND + c4);
        xt[row * 260 + c4 + 0] = v.x;
        xt[row * 260 + c4 + 1] = v.y;
        xt[row * 260 + c4 + 2] = v.z;
        xt[row * 260 + c4 + 3] = v.w;
    }

    // ---- W^T: i = bid>>1, o-half = (bid&1)*128; write WT[o][i] ----
    if (tid < 128) {
        const int i = bid >> 1, o = (bid & 1) * 128 + tid;
        const int io = i * OUTD + o;
        const float m = mask[io], b = sb[io], sp = ss[io];
        const float4* cp = reinterpret_cast<const float4*>(coef + (size_t)io * 8);
        const float4 c0 = cp[0], c1 = cp[1];
        const float wb = m * b, wsp = m * sp;
        const float c7 = c1.w;
        uint4 w;
        w.x = pack2(wb,                wsp * (c0.x - c7));
        w.y = pack2(wsp * (c0.y - c7), wsp * (c0.z - c7));
        w.z = pack2(wsp * (c0.w - c7), wsp * (c1.x - c7));
        w.w = pack2(wsp * (c1.y - c7), wsp * (c1.z - c7));
        WT[(size_t)o * IND + i] = w;
    }
    __syncthreads();

    // ---- F: 4 packs/thread, row-major F[b][i] (coalesced 4KB runs) ----
#pragma unroll
    for (int p = 0; p < 4; ++p)
        F[(size_t)(b0 + p) * IND + tid] = feat_pack(xt[p * 260 + tid]);

    // ---- bias: last 32 blocks, 8 o's each ----
    if (bid >= 480) {
        const int o0 = (bid - 480) * 8;
        const int ol = tid & 7, ig = tid >> 3;        // 32 i-groups of 8
        float s = 0.f;
#pragma unroll
        for (int ii = 0; ii < 8; ++ii) {
            const int i = ig * 8 + ii;
            const int io = i * OUTD + o0 + ol;
            s += mask[io] * ss[io] * coef[(size_t)io * 8 + 7];
        }
        part[ig][ol] = s;
        __syncthreads();
        if (tid < 8) {
            float acc = 0.f;
#pragma unroll
            for (int g2 = 0; g2 < 32; ++g2) acc += part[g2][tid];
            bias[o0 + tid] = acc;
        }
    }
}

// ============ kernel 2: LDS-staged GEMM ============
// 256 blocks x 1024 threads (16 waves = 4/SIMD). Block tile 64M x 32N, full K.
// XCD map: xcd=bid&7 -> 4 contiguous b0-tiles (F-slice 1MB L2-resident), o-tile=(bid>>3)&7.
// 16 waves = wm(2) x ks(8, K-split within chunk). 8 chunks of 32 i, double-buffered.
// Swizzle: LDS tile [row][32 packs]; stored(row,s) = logical(row, s^(row&7));
// staging pre-swizzles the GLOBAL src (rule 21), ds_read applies the same XOR.
__global__ __launch_bounds__(1024, 1) void kan_gemm(
    const uint4* __restrict__ F, const uint4* __restrict__ WT,
    const float* __restrict__ bias, float* __restrict__ out)
{
    __shared__ uint4 smem[6144];   // A: 2 x 2048 slots, W: 2 x 1024 slots (96KB)

    const int tid  = threadIdx.x;
    const int lane = tid & 63, wid = tid >> 6;
    const int wm = wid & 1, ks = wid >> 1;            // ks 0..7
    const int r = lane & 15, g = lane >> 4;
    const int bid = blockIdx.x;
    const int b0 = (((bid & 7) << 2) + (bid >> 6)) * 64;   // 32 M-tiles
    const int o0 = ((bid >> 3) & 7) * 32;                  // 8 N-tiles (one per XCD)

    // ---- staging sources (pre-swizzled global addresses) ----
    const int s0 = wid * 128 + lane;                 // A slots [wid*128, +64)
    const int s1 = s0 + 64;
    const int rA0 = s0 >> 5, cA0 = (s0 & 31) ^ (rA0 & 7);
    const int rA1 = s1 >> 5, cA1 = (s1 & 31) ^ (rA1 & 7);
    const int s2 = wid * 64 + lane;                  // W slots
    const int rW = s2 >> 5, cW = (s2 & 31) ^ (rW & 7);
    const uint4* pA0 = F  + (size_t)(b0 + rA0) * IND + cA0;
    const uint4* pA1 = F  + (size_t)(b0 + rA1) * IND + cA1;
    const uint4* pW  = WT + (size_t)(o0 + rW) * IND + cW;

    // ---- ds_read slot offsets (loop-invariant; swizzled) ----
    int aoff[2], woff[2];
#pragma unroll
    for (int mr = 0; mr < 2; ++mr) {
        const int arow = wm * 32 + mr * 16 + r;
        aoff[mr] = arow * 32 + ((ks * 4 + g) ^ (arow & 7));
    }
#pragma unroll
    for (int nr = 0; nr < 2; ++nr) {
        const int orow = nr * 16 + r;
        woff[nr] = orow * 32 + ((ks * 4 + g) ^ (orow & 7));
    }

    f32x4 acc[2][2] = {};

#define STAGE(t, buf)                                                              \
    {                                                                              \
        __builtin_amdgcn_global_load_lds((const AS1 uint*)(pA0 + (size_t)(t) * 32),\
            (AS3 uint*)(smem + (buf) * 2048 + wid * 128), 16, 0, 0);               \
        __builtin_amdgcn_global_load_lds((const AS1 uint*)(pA1 + (size_t)(t) * 32),\
            (AS3 uint*)(smem + (buf) * 2048 + wid * 128 + 64), 16, 0, 0);          \
        __builtin_amdgcn_global_load_lds((const AS1 uint*)(pW  + (size_t)(t) * 32),\
            (AS3 uint*)(smem + 4096 + (buf) * 1024 + wid * 64), 16, 0, 0);         \
    }

    STAGE(0, 0);
    for (int t = 0; t < 8; ++t) {
        __syncthreads();                         // stage(t) done; reads of t-1 done
        if (t < 7) STAGE(t + 1, (t + 1) & 1);
        const uint4* Ab = smem + (t & 1) * 2048;
        const uint4* Wb = smem + 4096 + (t & 1) * 1024;
        bf16x8 a0 = *reinterpret_cast<const bf16x8*>(Ab + aoff[0]);
        bf16x8 a1 = *reinterpret_cast<const bf16x8*>(Ab + aoff[1]);
        bf16x8 w0 = *reinterpret_cast<const bf16x8*>(Wb + woff[0]);
        bf16x8 w1 = *reinterpret_cast<const bf16x8*>(Wb + woff[1]);
        acc[0][0] = __builtin_amdgcn_mfma_f32_16x16x32_bf16(a0, w0, acc[0][0], 0, 0, 0);
        acc[0][1] = __builtin_amdgcn_mfma_f32_16x16x32_bf16(a0, w1, acc[0][1], 0, 0, 0);
        acc[1][0] = __builtin_amdgcn_mfma_f32_16x16x32_bf16(a1, w0, acc[1][0], 0, 0, 0);
        acc[1][1] = __builtin_amdgcn_mfma_f32_16x16x32_bf16(a1, w1, acc[1][1], 0, 0, 0);
    }
#undef STAGE

    // ---- epilogue: 8-way K-reduce via LDS (reuse smem), add bias, store ----
    __syncthreads();
    float* red = (float*)smem;                    // 2 x 7 x 1024 floats = 56KB
    if (ks > 0) {
        float* dst = red + (size_t)(wm * 7 + ks - 1) * 1024;
#pragma unroll
        for (int mf = 0; mf < 2; ++mf)
#pragma unroll
            for (int nf = 0; nf < 2; ++nf)
                *reinterpret_cast<f32x4*>(dst + (mf * 2 + nf) * 256 + lane * 4) = acc[mf][nf];
    }
    __syncthreads();
    if (ks == 0) {
#pragma unroll
        for (int mf = 0; mf < 2; ++mf)
#pragma unroll
            for (int nf = 0; nf < 2; ++nf) {
                f32x4 s = acc[mf][nf];
                const int sl = (mf * 2 + nf) * 256 + lane * 4;
#pragma unroll
                for (int kk = 0; kk < 7; ++kk) {
                    const f32x4 v = *reinterpret_cast<const f32x4*>(
                        red + (size_t)(wm * 7 + kk) * 1024 + sl);
                    s.x += v.x; s.y += v.y; s.z += v.z; s.w += v.w;
                }
                const int col  = o0 + nf * 16 + r;
                const int row0 = b0 + wm * 32 + mf * 16 + g * 4;
                const float bv = bias[col];
#pragma unroll
                for (int e = 0; e < 4; ++e)
                    out[(size_t)(row0 + e) * OUTD + col] = s[e] + bv;
            }
    }
}

// ============ fallback (used only if ws too small) ============
#define KPI  16
#define IPC  8
#define KC   (IPC * KPI)

__global__ __launch_bounds__(256, 2) void kan_mfma(
    const float* __restrict__ x, const float* __restrict__ coef,
    const float* __restrict__ scale_base, const float* __restrict__ scale_sp,
    const float* __restrict__ mask, float* __restrict__ out)
{
    const int tid = threadIdx.x;
    const int b0 = blockIdx.x * 32, o0 = blockIdx.y * 32;
    __shared__ uint Fa[32 * KC / 2];
    __shared__ uint Wt2[32 * KC / 2];
    for (int j = tid; j < 32 * KC / 2; j += 256) { Fa[j] = 0u; Wt2[j] = 0u; }
    const int lane = tid & 63, wid = tid >> 6;
    const int wmv = (wid >> 1) * 16, wnv = (wid & 1) * 16;
    f32x4 acc = {0.f, 0.f, 0.f, 0.f};
    const int fb = tid & 31, il = tid >> 5;
    for (int ic = 0; ic < IND / IPC; ++ic) {
        const int i = ic * IPC + il;
        __syncthreads();
        {
            const uint4 fp = feat_pack(x[(b0 + fb) * IND + i]);
            const int base = fb * (KC / 2) + il * (KPI / 2);
            const int sw = (fb & 7) << 2;
            Fa[(base + 0) ^ sw] = fp.x; Fa[(base + 1) ^ sw] = fp.y;
            Fa[(base + 2) ^ sw] = fp.z; Fa[(base + 3) ^ sw] = fp.w;
            ((ushort*)Fa)[2 * ((base + 4) ^ sw)] = 0;
        }
        {
            const int io = i * OUTD + o0 + fb;
            const float m = mask[io];
            const float wb = scale_base[io] * m, wsv = scale_sp[io] * m;
            const float4* cp = reinterpret_cast<const float4*>(coef + (size_t)io * 8);
            const float4 c0 = cp[0], c1 = cp[1];
            const float c7 = c1.w;
            const int base = fb * (KC / 2) + il * (KPI / 2);
            const int sw = (fb & 7) << 2;
            Wt2[(base + 0) ^ sw] = pack2(wb, wsv * (c0.x - c7));
            Wt2[(base + 1) ^ sw] = pack2(wsv * (c0.y - c7), wsv * (c0.z - c7));
            Wt2[(base + 2) ^ sw] = pack2(wsv * (c0.w - c7), wsv * (c1.x - c7));
            Wt2[(base + 3) ^ sw] = pack2(wsv * (c1.y - c7), wsv * (c1.z - c7));
            ((ushort*)Wt2)[2 * ((base + 4) ^ sw)] = 0;
        }
        __syncthreads();
        {
            const ushort* fs = (const ushort*)Fa;
            const ushort* wsd = (const ushort*)Wt2;
            const int ar = wmv + (lane & 15), br = wnv + (lane & 15);
            const int kg = (lane >> 4) * 8;
#pragma unroll
            for (int ksi = 0; ksi < 4; ++ksi) {
                const int ka = ksi * 32 + kg;
                const int ia = (ar * KC + ka) ^ ((ar & 7) << 3);
                const int ib = (br * KC + ka) ^ ((br & 7) << 3);
                bf16x8 a = *reinterpret_cast<const bf16x8*>(fs + ia);
                bf16x8 b = *reinterpret_cast<const bf16x8*>(wsd + ib);
                acc = __builtin_amdgcn_mfma_f32_16x16x32_bf16(a, b, acc, 0, 0, 0);
            }
        }
    }
    const int col = o0 + wnv + (lane & 15);
    const int row0 = b0 + wmv + ((lane >> 4) << 2);
    float bv = 0.f;
    for (int i = 0; i < IND; ++i) {
        const int io = i * OUTD + col;
        bv += mask[io] * scale_sp[io] * coef[(size_t)io * 8 + 7];
    }
#pragma unroll
    for (int rr = 0; rr < 4; ++rr)
        out[(size_t)(row0 + rr) * OUTD + col] = acc[rr] + bv;
}

extern "C" void kernel_launch(void* const* d_in, const int* in_sizes, int n_in,
                              void* d_out, int out_size, void* d_ws, size_t ws_size,
                              hipStream_t stream) {
    const float* x          = (const float*)d_in[0];
    const float* coef       = (const float*)d_in[2];
    const float* scale_base = (const float*)d_in[3];
    const float* scale_sp   = (const float*)d_in[4];
    const float* mask       = (const float*)d_in[5];
    float* out = (float*)d_out;

    if (ws_size >= WS_NEED) {
        uint4* WT   = (uint4*)d_ws;
        float* bias = (float*)((char*)d_ws + BIASOFF);
        uint4* F    = (uint4*)((char*)d_ws + FOFF);
        kan_prep<<<512, 256, 0, stream>>>(x, coef, scale_base, scale_sp, mask, WT, bias, F);
        kan_gemm<<<256, 1024, 0, stream>>>(F, WT, bias, out);
    } else {
        kan_mfma<<<dim3(BATCH / 32, OUTD / 32), 256, 0, stream>>>(
            x, coef, scale_base, scale_sp, mask, out);
    }
}